// Round 3
// baseline (458.604 us; speedup 1.0000x reference)
//
#include <hip/hip_runtime.h>
#include <hip/hip_bf16.h>

#define DIM 64
#define NEG_HUGE (-3.402823466e+38f)

typedef __attribute__((ext_vector_type(8))) short bf16x8;
typedef __attribute__((ext_vector_type(4))) float f32x4;

__device__ __forceinline__ unsigned short f2bf(float f) {
    unsigned u = __float_as_uint(f);
    u += 0x7FFFu + ((u >> 16) & 1u);   // round-to-nearest-even
    return (unsigned short)(u >> 16);
}

__device__ __forceinline__ bool better_vi(float v, int i, float v2, int i2) {
    return (v > v2) || (v == v2 && i < i2);
}

__device__ __forceinline__ void ins3_cmp(float s, int idx,
                                         float& v0, int& i0, float& v1, int& i1,
                                         float& v2, int& i2) {
    if (better_vi(s, idx, v2, i2)) {
        if (better_vi(s, idx, v1, i1)) {
            v2 = v1; i2 = i1;
            if (better_vi(s, idx, v0, i0)) { v1 = v0; i1 = i0; v0 = s; i0 = idx; }
            else                            { v1 = s;  i1 = idx; }
        } else { v2 = s; i2 = idx; }
    }
}

// ---------- kernel 0: q_unit = emb / ||emb|| ----------
__global__ void qunit_kernel(const float* __restrict__ emb, float* __restrict__ qu) {
    int b = blockIdx.x, d = threadIdx.x;          // 64 threads/block
    float x = emb[b * DIM + d];
    float s = x * x;
    #pragma unroll
    for (int off = 32; off > 0; off >>= 1) s += __shfl_xor(s, off);
    float inv = (s > 0.f) ? (1.0f / sqrtf(s)) : 1.0f;
    qu[b * DIM + d] = x * inv;
}

// ---------- kernel 1: bf16-MFMA scoring + per-block approx top-3 ----------
// 256 threads (4 waves), each wave owns 64 queries. Double-buffered LDS tile,
// 2-deep register prefetch, ONE barrier per 64-row chunk.
__global__ __launch_bounds__(256, 4)
void score_topk_kernel(const float* __restrict__ kb,
                       const float* __restrict__ qunit,
                       float* __restrict__ tv,   // [256][NB][3] approx values
                       int*   __restrict__ ti,   // [256][NB][3] row indices
                       int NB, int N, int rpb) {
    __shared__ unsigned char bufA[64 * 128];      // 64 rows x 64 bf16, XOR-swizzled
    __shared__ unsigned char bufB[64 * 128];

    const int t    = threadIdx.x;
    const int lane = t & 63;
    const int w    = t >> 6;                      // wave 0..3
    const int blk  = blockIdx.x;
    const long r0  = (long)blk * (long)rpb;
    const long r1  = min((long)N, r0 + (long)rpb);
    const float4* kb4 = (const float4*)kb;

    // ---- A fragments: queries [64w, 64w+64) in bf16 (RNE), resident in VGPRs ----
    bf16x8 afr[4][2];
    {
        const int qrow = lane & 15;
        const int k0   = (lane >> 4) * 8;
        #pragma unroll
        for (int qt = 0; qt < 4; qt++) {
            int q = (4 * w + qt) * 16 + qrow;
            #pragma unroll
            for (int kh = 0; kh < 2; kh++) {
                const float* src = qunit + (size_t)q * DIM + k0 + kh * 32;
                float4 f0 = *(const float4*)(src);
                float4 f1 = *(const float4*)(src + 4);
                bf16x8 a;
                a[0] = (short)f2bf(f0.x); a[1] = (short)f2bf(f0.y);
                a[2] = (short)f2bf(f0.z); a[3] = (short)f2bf(f0.w);
                a[4] = (short)f2bf(f1.x); a[5] = (short)f2bf(f1.y);
                a[6] = (short)f2bf(f1.z); a[7] = (short)f2bf(f1.w);
                afr[qt][kh] = a;
            }
        }
    }

    // per-(lane,query) top-2 tagged scores
    float v1[4][4], v2[4][4];
    #pragma unroll
    for (int a = 0; a < 4; a++)
        #pragma unroll
        for (int b = 0; b < 4; b++) { v1[a][b] = NEG_HUGE; v2[a][b] = NEG_HUGE; }

    const long drows = r1 - r0;
    const int  nch   = (drows > 0) ? (int)((drows + 63) >> 6) : 0;   // <= 16

    const int hb   = (lane >> 4) * 16;     // byte col base of B-frag
    const int brow = lane & 15;

#define LOAD_CHUNK(dst, ch) do {                                               \
    long _base = r0 + (long)(ch) * 64;                                         \
    _Pragma("unroll")                                                          \
    for (int _j = 0; _j < 4; _j++) {                                           \
        int  _f4 = t + 256 * _j;                                               \
        long _vr = _base + (_f4 >> 4);                                         \
        dst[_j] = (_vr < r1) ? kb4[_vr * 16 + (_f4 & 15)]                      \
                             : make_float4(0.f, 0.f, 0.f, 0.f);                \
    }                                                                          \
} while (0)

    // write phase: row norm (16-lane butterfly), scale, truncate->bf16 via v_perm
#define WRITE_PHASE(buf, ld) do {                                              \
    _Pragma("unroll")                                                          \
    for (int _j = 0; _j < 4; _j++) {                                           \
        float _s = ld[_j].x * ld[_j].x + ld[_j].y * ld[_j].y                   \
                 + ld[_j].z * ld[_j].z + ld[_j].w * ld[_j].w;                  \
        _Pragma("unroll")                                                      \
        for (int _o = 1; _o < 16; _o <<= 1) _s += __shfl_xor(_s, _o);          \
        float _ri = (_s > 0.f) ? rsqrtf(_s) : 1.0f;                            \
        unsigned _a = __float_as_uint(ld[_j].x * _ri);                         \
        unsigned _b = __float_as_uint(ld[_j].y * _ri);                         \
        unsigned _c = __float_as_uint(ld[_j].z * _ri);                         \
        unsigned _d = __float_as_uint(ld[_j].w * _ri);                         \
        uint2 _pk;                                                             \
        _pk.x = __builtin_amdgcn_perm(_b, _a, 0x07060302u);                    \
        _pk.y = __builtin_amdgcn_perm(_d, _c, 0x07060302u);                    \
        int _row  = (t >> 4) + 16 * _j;                                        \
        int _col8 = (t & 15) * 8;                                              \
        int _byte = _row * 128 + (_col8 ^ ((_row & 7) << 4));                  \
        *(uint2*)(buf + _byte) = _pk;                                          \
    }                                                                          \
} while (0)

#define MFMA_PHASE(buf, cc) do {                                               \
    const unsigned _tb = (unsigned)((cc) << 2);                                \
    _Pragma("unroll")                                                          \
    for (int _rt = 0; _rt < 4; _rt++) {                                        \
        int _row = _rt * 16 + brow;                                            \
        int _sw  = (_row & 7) << 4;                                            \
        bf16x8 _b0 = *(const bf16x8*)(buf + _row * 128 + ((hb     ) ^ _sw));   \
        bf16x8 _b1 = *(const bf16x8*)(buf + _row * 128 + ((hb + 64) ^ _sw));   \
        const unsigned _tag = _tb | (unsigned)_rt;                             \
        _Pragma("unroll")                                                      \
        for (int _qt = 0; _qt < 4; _qt++) {                                    \
            f32x4 _acc = {0.f, 0.f, 0.f, 0.f};                                 \
            _acc = __builtin_amdgcn_mfma_f32_16x16x32_bf16(afr[_qt][0], _b0, _acc, 0, 0, 0); \
            _acc = __builtin_amdgcn_mfma_f32_16x16x32_bf16(afr[_qt][1], _b1, _acc, 0, 0, 0); \
            _Pragma("unroll")                                                  \
            for (int _j = 0; _j < 4; _j++) {                                   \
                float _x  = _acc[_j];                                          \
                float _xt = __uint_as_float((__float_as_uint(_x) & 0xFFFFFF00u) | _tag); \
                float _mn = fminf(_xt, v1[_qt][_j]);                           \
                v1[_qt][_j] = fmaxf(_xt, v1[_qt][_j]);                         \
                v2[_qt][_j] = fmaxf(v2[_qt][_j], _mn);                         \
            }                                                                  \
        }                                                                      \
    }                                                                          \
} while (0)

    if (nch > 0) {
        float4 ldA[4], ldB[4];
        LOAD_CHUNK(ldA, 0);
        LOAD_CHUNK(ldB, 1);
        WRITE_PHASE(bufA, ldA);       // chunk 0 -> bufA
        LOAD_CHUNK(ldA, 2);           // 2-deep prefetch
        __syncthreads();

        for (int c = 0; c < nch; c += 2) {
            // even half: stage chunk c+1, compute chunk c
            WRITE_PHASE(bufB, ldB);               // chunk c+1 (zero-padded past end)
            LOAD_CHUNK(ldB, c + 3);
            MFMA_PHASE(bufA, c);
            __syncthreads();
            if (c + 1 < nch) {
                // odd half: stage chunk c+2, compute chunk c+1
                WRITE_PHASE(bufA, ldA);           // chunk c+2
                LOAD_CHUNK(ldA, c + 4);
                MFMA_PHASE(bufB, c + 1);
                __syncthreads();
            }
        }
    }

#undef LOAD_CHUNK
#undef WRITE_PHASE
#undef MFMA_PHASE

    // ---- reduce: per query, merge 16 lanes x top-2 -> block top-3, write out ----
    #pragma unroll
    for (int qt = 0; qt < 4; qt++) {
        #pragma unroll
        for (int j = 0; j < 4; j++) {
            float bv0 = NEG_HUGE, bv1 = NEG_HUGE, bv2 = NEG_HUGE;
            int   bi0 = 0, bi1 = 0, bi2 = 0;
            #pragma unroll
            for (int s = 0; s < 2; s++) {
                float vv = s ? v2[qt][j] : v1[qt][j];
                if (vv != NEG_HUGE) {
                    unsigned tag = __float_as_uint(vv) & 0xFFu;
                    long row = r0 + (long)(tag >> 2) * 64 + (long)(tag & 3u) * 16 + (lane & 15);
                    if (row < r1) ins3_cmp(vv, (int)row, bv0, bi0, bv1, bi1, bv2, bi2);
                }
            }
            #pragma unroll
            for (int off = 1; off < 16; off <<= 1) {
                float w0 = __shfl_xor(bv0, off), w1 = __shfl_xor(bv1, off), w2 = __shfl_xor(bv2, off);
                int   x0 = __shfl_xor(bi0, off), x1 = __shfl_xor(bi1, off), x2 = __shfl_xor(bi2, off);
                ins3_cmp(w0, x0, bv0, bi0, bv1, bi1, bv2, bi2);
                ins3_cmp(w1, x1, bv0, bi0, bv1, bi1, bv2, bi2);
                ins3_cmp(w2, x2, bv0, bi0, bv1, bi1, bv2, bi2);
            }
            if ((lane & 15) == 0) {
                int q = (4 * w + qt) * 16 + (lane >> 4) * 4 + j;
                size_t o = ((size_t)q * NB + blk) * 3;
                tv[o] = bv0; tv[o + 1] = bv1; tv[o + 2] = bv2;
                ti[o] = bi0; ti[o + 1] = bi1; ti[o + 2] = bi2;
            }
        }
    }
}

// ---------- kernel 2: merge approx candidates, exact f32 rescore, context ----------
__global__ __launch_bounds__(256)
void merge_rescore_kernel(const float* __restrict__ tv, const int* __restrict__ ti,
                          const float* __restrict__ kb, const float* __restrict__ qunit,
                          float* __restrict__ ctx_out, int NB, int N) {
    __shared__ float sq[DIM];
    __shared__ float swv[4][3];
    __shared__ int   swi[4][3];
    __shared__ float s_tau;
    __shared__ int   s_cnt;
    __shared__ float cv[64];
    __shared__ int   ci[64];
    __shared__ int   fidx[3];

    const int q = blockIdx.x, t = threadIdx.x;
    if (t < DIM) sq[t] = qunit[(size_t)q * DIM + t];
    if (t == 0) s_cnt = 0;
    const float* tvq = tv + (size_t)q * NB * 3;
    const int*   tiq = ti + (size_t)q * NB * 3;
    const int total = NB * 3;

    float v0 = NEG_HUGE, v1 = NEG_HUGE, v2 = NEG_HUGE;
    int   i0 = 0, i1 = 0, i2 = 0;
    for (int c = t; c < total; c += 256)
        ins3_cmp(tvq[c], tiq[c], v0, i0, v1, i1, v2, i2);
    #pragma unroll
    for (int off = 1; off < 64; off <<= 1) {
        float w0 = __shfl_xor(v0, off), w1 = __shfl_xor(v1, off), w2 = __shfl_xor(v2, off);
        int   x0 = __shfl_xor(i0, off), x1 = __shfl_xor(i1, off), x2 = __shfl_xor(i2, off);
        ins3_cmp(w0, x0, v0, i0, v1, i1, v2, i2);
        ins3_cmp(w1, x1, v0, i0, v1, i1, v2, i2);
        ins3_cmp(w2, x2, v0, i0, v1, i1, v2, i2);
    }
    if ((t & 63) == 0) {
        int wv = t >> 6;
        swv[wv][0] = v0; swv[wv][1] = v1; swv[wv][2] = v2;
        swi[wv][0] = i0; swi[wv][1] = i1; swi[wv][2] = i2;
    }
    __syncthreads();
    if (t == 0) {
        float a0 = NEG_HUGE, a1 = NEG_HUGE, a2 = NEG_HUGE;
        int   b0 = 0, b1 = 0, b2 = 0;
        for (int wv = 0; wv < 4; wv++)
            for (int r = 0; r < 3; r++)
                ins3_cmp(swv[wv][r], swi[wv][r], a0, b0, a1, b1, a2, b2);
        s_tau = a2 - 0.03f;    // margin >> bf16-truncation approx error (~0.008)
    }
    __syncthreads();
    const float tau = s_tau;

    for (int c = t; c < total; c += 256) {
        float av = tvq[c];
        if (av >= tau) {
            int idx = tiq[c];
            const float4* kr = (const float4*)kb + (size_t)idx * 16;
            const float4* qr = (const float4*)sq;
            float dot = 0.f, ss = 0.f;
            #pragma unroll
            for (int d = 0; d < 16; d++) {
                float4 kv = kr[d], qv = qr[d];
                dot += kv.x * qv.x + kv.y * qv.y + kv.z * qv.z + kv.w * qv.w;
                ss  += kv.x * kv.x + kv.y * kv.y + kv.z * kv.z + kv.w * kv.w;
            }
            float ex = dot * ((ss > 0.f) ? (1.0f / sqrtf(ss)) : 1.0f);
            int slot = atomicAdd(&s_cnt, 1);
            if (slot < 64) { cv[slot] = ex; ci[slot] = idx; }
        }
    }
    __syncthreads();
    if (t == 0) {
        float f0 = NEG_HUGE, f1 = NEG_HUGE, f2 = NEG_HUGE;
        int   g0 = 0, g1 = 0, g2 = 0;
        int n = s_cnt < 64 ? s_cnt : 64;
        for (int c = 0; c < n; c++)
            ins3_cmp(cv[c], ci[c], f0, g0, f1, g1, f2, g2);
        fidx[0] = g0; fidx[1] = g1; fidx[2] = g2;
    }
    __syncthreads();
    if (t < DIM) {
        float c0 = kb[(size_t)fidx[0] * DIM + t];
        float c1 = kb[(size_t)fidx[1] * DIM + t];
        float c2 = kb[(size_t)fidx[2] * DIM + t];
        ctx_out[(size_t)q * DIM + t] = ((c0 + c1) + c2) / 3.0f;
    }
}

// ---------- kernel 3: MLP tail (attn == 1 identically; q/k are dead code) ----------
__global__ void mlp_kernel(const float* __restrict__ emb,
                           const float* __restrict__ ctx,
                           const float* __restrict__ in_proj_w,
                           const float* __restrict__ in_proj_b,
                           const float* __restrict__ out_w,
                           const float* __restrict__ out_b,
                           const float* __restrict__ ci_w1,
                           const float* __restrict__ ci_b1,
                           const float* __restrict__ ci_w2,
                           const float* __restrict__ ci_b2,
                           const float* __restrict__ cls_w1,
                           const float* __restrict__ cls_b1,
                           const float* __restrict__ cls_w2,
                           const float* __restrict__ cls_b2,
                           float* __restrict__ pred) {
    __shared__ float se[64], sc[64], sv[64], sa[64], sh[64], senh[64], scc[128];
    const int b = blockIdx.x, t = threadIdx.x;

    if (t < 64) { se[t] = emb[b * 64 + t]; sc[t] = ctx[b * 64 + t]; }
    __syncthreads();
    if (t < 64) {
        const float* w = in_proj_w + (size_t)(128 + t) * 64;
        float s = in_proj_b[128 + t];
        #pragma unroll 8
        for (int d = 0; d < 64; d++) s += sc[d] * w[d];
        sv[t] = s;
    }
    __syncthreads();
    if (t < 64) {
        const float* w = out_w + (size_t)t * 64;
        float s = out_b[t];
        #pragma unroll 8
        for (int d = 0; d < 64; d++) s += sv[d] * w[d];
        sa[t] = s;
    }
    __syncthreads();
    if (t < 64) {
        const float* w = ci_w1 + (size_t)t * 128;
        float s = ci_b1[t];
        #pragma unroll 8
        for (int d = 0; d < 64; d++) s += se[d] * w[d];
        #pragma unroll 8
        for (int d = 0; d < 64; d++) s += sa[d] * w[64 + d];
        sh[t] = fmaxf(s, 0.f);
    }
    __syncthreads();
    if (t < 64) {
        const float* w = ci_w2 + (size_t)t * 64;
        float s = ci_b2[t];
        #pragma unroll 8
        for (int d = 0; d < 64; d++) s += sh[d] * w[d];
        senh[t] = s;
    }
    __syncthreads();
    {
        const float* w = cls_w1 + (size_t)t * 64;
        float s = cls_b1[t];
        #pragma unroll 8
        for (int d = 0; d < 64; d++) s += senh[d] * w[d];
        scc[t] = fmaxf(s, 0.f);
    }
    __syncthreads();
    if (t < 2) {
        const float* w = cls_w2 + (size_t)t * 128;
        float s = cls_b2[t];
        for (int d = 0; d < 128; d++) s += scc[d] * w[d];
        pred[b * 2 + t] = s;
    }
}

extern "C" void kernel_launch(void* const* d_in, const int* in_sizes, int n_in,
                              void* d_out, int out_size, void* d_ws, size_t ws_size,
                              hipStream_t stream) {
    const float* emb       = (const float*)d_in[0];
    const float* kb        = (const float*)d_in[1];
    const float* in_proj_w = (const float*)d_in[2];
    const float* in_proj_b = (const float*)d_in[3];
    const float* out_w     = (const float*)d_in[4];
    const float* out_b     = (const float*)d_in[5];
    const float* ci_w1     = (const float*)d_in[6];
    const float* ci_b1     = (const float*)d_in[7];
    const float* ci_w2     = (const float*)d_in[8];
    const float* ci_b2     = (const float*)d_in[9];
    const float* cls_w1    = (const float*)d_in[10];
    const float* cls_b1    = (const float*)d_in[11];
    const float* cls_w2    = (const float*)d_in[12];
    const float* cls_b2    = (const float*)d_in[13];
    float* out = (float*)d_out;

    const int Bq = in_sizes[0] / DIM;   // 256
    const int N  = in_sizes[1] / DIM;   // 1,000,000

    float* qunit = (float*)d_ws;
    const size_t qunit_bytes = (size_t)Bq * DIM * 4;
    long avail = (long)ws_size - (long)qunit_bytes;
    int NB = (int)(avail / ((long)Bq * 3 * 8));
    if (NB > 1024) NB = 1024;
    if (NB < 1)    NB = 1;
    float* tv = qunit + (size_t)Bq * DIM;
    int*   ti = (int*)(tv + (size_t)Bq * NB * 3);
    const int rpb = (N + NB - 1) / NB;   // NB=1024 -> rpb=977 -> nch=16 (tag fits 6 bits)

    float* ctx_out  = out + (size_t)Bq * 2;
    float* pred_out = out;

    qunit_kernel<<<Bq, 64, 0, stream>>>(emb, qunit);
    score_topk_kernel<<<NB, 256, 0, stream>>>(kb, qunit, tv, ti, NB, N, rpb);
    merge_rescore_kernel<<<Bq, 256, 0, stream>>>(tv, ti, kb, qunit, ctx_out, NB, N);
    mlp_kernel<<<Bq, 128, 0, stream>>>(emb, ctx_out, in_proj_w, in_proj_b,
                                       out_w, out_b, ci_w1, ci_b1, ci_w2, ci_b2,
                                       cls_w1, cls_b1, cls_w2, cls_b2, pred_out);
}

// Round 4
// 284.786 us; speedup vs baseline: 1.6103x; 1.6103x over previous
//
#include <hip/hip_runtime.h>
#include <hip/hip_bf16.h>

#define DIM 64
#define NEG_HUGE (-3.402823466e+38f)
#define QSPLIT 2

typedef __attribute__((ext_vector_type(8))) short bf16x8;
typedef __attribute__((ext_vector_type(4))) float f32x4;

__device__ __forceinline__ unsigned short f2bf(float f) {
    unsigned u = __float_as_uint(f);
    u += 0x7FFFu + ((u >> 16) & 1u);   // round-to-nearest-even
    return (unsigned short)(u >> 16);
}

__device__ __forceinline__ bool better_vi(float v, int i, float v2, int i2) {
    return (v > v2) || (v == v2 && i < i2);
}

__device__ __forceinline__ void ins3_cmp(float s, int idx,
                                         float& v0, int& i0, float& v1, int& i1,
                                         float& v2, int& i2) {
    if (better_vi(s, idx, v2, i2)) {
        if (better_vi(s, idx, v1, i1)) {
            v2 = v1; i2 = i1;
            if (better_vi(s, idx, v0, i0)) { v1 = v0; i1 = i0; v0 = s; i0 = idx; }
            else                            { v1 = s;  i1 = idx; }
        } else { v2 = s; i2 = idx; }
    }
}

// ---------- kernel 0: q_unit = emb / ||emb|| ----------
__global__ void qunit_kernel(const float* __restrict__ emb, float* __restrict__ qu) {
    int b = blockIdx.x, d = threadIdx.x;          // 64 threads/block
    float x = emb[b * DIM + d];
    float s = x * x;
    #pragma unroll
    for (int off = 32; off > 0; off >>= 1) s += __shfl_xor(s, off);
    float inv = (s > 0.f) ? (1.0f / sqrtf(s)) : 1.0f;
    qu[b * DIM + d] = x * inv;
}

// ---------- kernel 1: bf16-MFMA scoring + per-block approx top-3 ----------
// Grid = NB * QSPLIT. Block handles 128 queries (qs half) over chunk-block cb.
// 256 threads (4 waves); each wave owns 32 queries (2 query-tiles of 16).
// Round-2 proven structure: single 8KB LDS tile, 1-deep reg prefetch,
// 2 barriers/chunk. Parallelism comes from 8 blocks/CU.
__global__ __launch_bounds__(256, 3)
void score_topk_kernel(const float* __restrict__ kb,
                       const float* __restrict__ qunit,
                       float* __restrict__ tv,   // [256][NB][3] approx values
                       int*   __restrict__ ti,   // [256][NB][3] row indices
                       int NB, int N, int rpb) {
    __shared__ unsigned char ktile[64 * 128];     // 64 rows x 64 bf16, XOR-swizzled

    const int t    = threadIdx.x;
    const int lane = t & 63;
    const int w    = t >> 6;                      // wave 0..3
    const int cb   = blockIdx.x >> 1;             // chunk-block 0..NB-1
    const int qs   = blockIdx.x & 1;              // query half
    const int qbase = qs * 128;
    const long r0  = (long)cb * (long)rpb;
    const long r1  = min((long)N, r0 + (long)rpb);
    const float4* kb4 = (const float4*)kb;

    // ---- A fragments: this block's 32-per-wave queries in bf16 (RNE) ----
    bf16x8 afr[2][2];
    {
        const int qrow = lane & 15;
        const int k0   = (lane >> 4) * 8;
        #pragma unroll
        for (int qt = 0; qt < 2; qt++) {
            int q = qbase + (2 * w + qt) * 16 + qrow;
            #pragma unroll
            for (int kh = 0; kh < 2; kh++) {
                const float* src = qunit + (size_t)q * DIM + k0 + kh * 32;
                float4 f0 = *(const float4*)(src);
                float4 f1 = *(const float4*)(src + 4);
                bf16x8 a;
                a[0] = (short)f2bf(f0.x); a[1] = (short)f2bf(f0.y);
                a[2] = (short)f2bf(f0.z); a[3] = (short)f2bf(f0.w);
                a[4] = (short)f2bf(f1.x); a[5] = (short)f2bf(f1.y);
                a[6] = (short)f2bf(f1.z); a[7] = (short)f2bf(f1.w);
                afr[qt][kh] = a;
            }
        }
    }

    // per-(lane,query) top-2 tagged scores
    float v1[2][4], v2[2][4];
    #pragma unroll
    for (int a = 0; a < 2; a++)
        #pragma unroll
        for (int b = 0; b < 4; b++) { v1[a][b] = NEG_HUGE; v2[a][b] = NEG_HUGE; }

    const long drows = r1 - r0;
    const int  nch   = (drows > 0) ? (int)((drows + 63) >> 6) : 0;   // <= 16

    // prefetch chunk 0 (global -> regs)
    float4 ld[4];
    #pragma unroll
    for (int j = 0; j < 4; j++) {
        int f4 = t + 256 * j;
        long vrow = r0 + (f4 >> 4);
        ld[j] = (vrow < r1) ? kb4[vrow * 16 + (f4 & 15)]
                            : make_float4(0.f, 0.f, 0.f, 0.f);
    }

    const int hb   = (lane >> 4) * 16;     // byte col base of B-frag
    const int brow = lane & 15;

    for (int c = 0; c < nch; c++) {
        // ---- write phase: row norms (16-lane butterfly), scale, bf16 (trunc), swizzled ----
        #pragma unroll
        for (int j = 0; j < 4; j++) {
            float s = ld[j].x * ld[j].x + ld[j].y * ld[j].y
                    + ld[j].z * ld[j].z + ld[j].w * ld[j].w;
            #pragma unroll
            for (int off = 1; off < 16; off <<= 1) s += __shfl_xor(s, off);
            float ri = (s > 0.f) ? rsqrtf(s) : 1.0f;
            unsigned ua = __float_as_uint(ld[j].x * ri);
            unsigned ub = __float_as_uint(ld[j].y * ri);
            unsigned uc = __float_as_uint(ld[j].z * ri);
            unsigned ud = __float_as_uint(ld[j].w * ri);
            uint2 pk;
            pk.x = __builtin_amdgcn_perm(ub, ua, 0x07060302u);  // hi16(a)|hi16(b)
            pk.y = __builtin_amdgcn_perm(ud, uc, 0x07060302u);
            int row  = (t >> 4) + 16 * j;                     // 0..63
            int col8 = (t & 15) * 8;                          // byte offset of 4 bf16
            int byte = row * 128 + (col8 ^ ((row & 7) << 4)); // XOR swizzle (bits 4-6)
            *(uint2*)(ktile + byte) = pk;
        }
        __syncthreads();   // tile ready

        // ---- prefetch next chunk (overlaps MFMA below) ----
        if (c + 1 < nch) {
            long base = r0 + (long)(c + 1) * 64;
            #pragma unroll
            for (int j = 0; j < 4; j++) {
                int f4 = t + 256 * j;
                long vrow = base + (f4 >> 4);
                ld[j] = (vrow < r1) ? kb4[vrow * 16 + (f4 & 15)]
                                    : make_float4(0.f, 0.f, 0.f, 0.f);
            }
        }

        // ---- score: 4 row-tiles x 2 query-tiles, K=64 in two MFMAs ----
        const unsigned tagbase = (unsigned)(c << 2);
        #pragma unroll
        for (int rt = 0; rt < 4; rt++) {
            int row = rt * 16 + brow;
            int sw  = (row & 7) << 4;
            bf16x8 bf0 = *(const bf16x8*)(ktile + row * 128 + ((hb     ) ^ sw));
            bf16x8 bf1 = *(const bf16x8*)(ktile + row * 128 + ((hb + 64) ^ sw));
            const unsigned tag = tagbase | (unsigned)rt;
            #pragma unroll
            for (int qt = 0; qt < 2; qt++) {
                f32x4 acc = {0.f, 0.f, 0.f, 0.f};
                acc = __builtin_amdgcn_mfma_f32_16x16x32_bf16(afr[qt][0], bf0, acc, 0, 0, 0);
                acc = __builtin_amdgcn_mfma_f32_16x16x32_bf16(afr[qt][1], bf1, acc, 0, 0, 0);
                #pragma unroll
                for (int j = 0; j < 4; j++) {
                    float x  = acc[j];
                    float xt = __uint_as_float((__float_as_uint(x) & 0xFFFFFF00u) | tag);
                    float mn = fminf(xt, v1[qt][j]);
                    v1[qt][j] = fmaxf(xt, v1[qt][j]);
                    v2[qt][j] = fmaxf(v2[qt][j], mn);
                }
            }
        }
        __syncthreads();   // all reads done before next overwrite
    }

    // ---- reduce: per query, merge 16 lanes x top-2 -> block top-3, write out ----
    #pragma unroll
    for (int qt = 0; qt < 2; qt++) {
        #pragma unroll
        for (int j = 0; j < 4; j++) {
            float bv0 = NEG_HUGE, bv1 = NEG_HUGE, bv2 = NEG_HUGE;
            int   bi0 = 0, bi1 = 0, bi2 = 0;
            #pragma unroll
            for (int s = 0; s < 2; s++) {
                float vv = s ? v2[qt][j] : v1[qt][j];
                if (vv != NEG_HUGE) {
                    unsigned tag = __float_as_uint(vv) & 0xFFu;
                    long row = r0 + (long)(tag >> 2) * 64 + (long)(tag & 3u) * 16 + (lane & 15);
                    if (row < r1) ins3_cmp(vv, (int)row, bv0, bi0, bv1, bi1, bv2, bi2);
                }
            }
            #pragma unroll
            for (int off = 1; off < 16; off <<= 1) {
                float w0 = __shfl_xor(bv0, off), w1 = __shfl_xor(bv1, off), w2 = __shfl_xor(bv2, off);
                int   x0 = __shfl_xor(bi0, off), x1 = __shfl_xor(bi1, off), x2 = __shfl_xor(bi2, off);
                ins3_cmp(w0, x0, bv0, bi0, bv1, bi1, bv2, bi2);
                ins3_cmp(w1, x1, bv0, bi0, bv1, bi1, bv2, bi2);
                ins3_cmp(w2, x2, bv0, bi0, bv1, bi1, bv2, bi2);
            }
            if ((lane & 15) == 0) {
                int q = qbase + (2 * w + qt) * 16 + (lane >> 4) * 4 + j;
                size_t o = ((size_t)q * NB + cb) * 3;
                tv[o] = bv0; tv[o + 1] = bv1; tv[o + 2] = bv2;
                ti[o] = bi0; ti[o + 1] = bi1; ti[o + 2] = bi2;
            }
        }
    }
}

// ---------- kernel 2: merge approx candidates, exact f32 rescore, context ----------
__global__ __launch_bounds__(256)
void merge_rescore_kernel(const float* __restrict__ tv, const int* __restrict__ ti,
                          const float* __restrict__ kb, const float* __restrict__ qunit,
                          float* __restrict__ ctx_out, int NB, int N) {
    __shared__ float sq[DIM];
    __shared__ float swv[4][3];
    __shared__ int   swi[4][3];
    __shared__ float s_tau;
    __shared__ int   s_cnt;
    __shared__ float cv[64];
    __shared__ int   ci[64];
    __shared__ int   fidx[3];

    const int q = blockIdx.x, t = threadIdx.x;
    if (t < DIM) sq[t] = qunit[(size_t)q * DIM + t];
    if (t == 0) s_cnt = 0;
    const float* tvq = tv + (size_t)q * NB * 3;
    const int*   tiq = ti + (size_t)q * NB * 3;
    const int total = NB * 3;

    float v0 = NEG_HUGE, v1 = NEG_HUGE, v2 = NEG_HUGE;
    int   i0 = 0, i1 = 0, i2 = 0;
    for (int c = t; c < total; c += 256)
        ins3_cmp(tvq[c], tiq[c], v0, i0, v1, i1, v2, i2);
    #pragma unroll
    for (int off = 1; off < 64; off <<= 1) {
        float w0 = __shfl_xor(v0, off), w1 = __shfl_xor(v1, off), w2 = __shfl_xor(v2, off);
        int   x0 = __shfl_xor(i0, off), x1 = __shfl_xor(i1, off), x2 = __shfl_xor(i2, off);
        ins3_cmp(w0, x0, v0, i0, v1, i1, v2, i2);
        ins3_cmp(w1, x1, v0, i0, v1, i1, v2, i2);
        ins3_cmp(w2, x2, v0, i0, v1, i1, v2, i2);
    }
    if ((t & 63) == 0) {
        int wv = t >> 6;
        swv[wv][0] = v0; swv[wv][1] = v1; swv[wv][2] = v2;
        swi[wv][0] = i0; swi[wv][1] = i1; swi[wv][2] = i2;
    }
    __syncthreads();
    if (t == 0) {
        float a0 = NEG_HUGE, a1 = NEG_HUGE, a2 = NEG_HUGE;
        int   b0 = 0, b1 = 0, b2 = 0;
        for (int wv = 0; wv < 4; wv++)
            for (int r = 0; r < 3; r++)
                ins3_cmp(swv[wv][r], swi[wv][r], a0, b0, a1, b1, a2, b2);
        s_tau = a2 - 0.03f;    // margin >> bf16-truncation approx error (~0.008)
    }
    __syncthreads();
    const float tau = s_tau;

    for (int c = t; c < total; c += 256) {
        float av = tvq[c];
        if (av >= tau) {
            int idx = tiq[c];
            const float4* kr = (const float4*)kb + (size_t)idx * 16;
            const float4* qr = (const float4*)sq;
            float dot = 0.f, ss = 0.f;
            #pragma unroll
            for (int d = 0; d < 16; d++) {
                float4 kv = kr[d], qv = qr[d];
                dot += kv.x * qv.x + kv.y * qv.y + kv.z * qv.z + kv.w * qv.w;
                ss  += kv.x * kv.x + kv.y * kv.y + kv.z * kv.z + kv.w * kv.w;
            }
            float ex = dot * ((ss > 0.f) ? (1.0f / sqrtf(ss)) : 1.0f);
            int slot = atomicAdd(&s_cnt, 1);
            if (slot < 64) { cv[slot] = ex; ci[slot] = idx; }
        }
    }
    __syncthreads();
    if (t == 0) {
        float f0 = NEG_HUGE, f1 = NEG_HUGE, f2 = NEG_HUGE;
        int   g0 = 0, g1 = 0, g2 = 0;
        int n = s_cnt < 64 ? s_cnt : 64;
        for (int c = 0; c < n; c++)
            ins3_cmp(cv[c], ci[c], f0, g0, f1, g1, f2, g2);
        fidx[0] = g0; fidx[1] = g1; fidx[2] = g2;
    }
    __syncthreads();
    if (t < DIM) {
        float c0 = kb[(size_t)fidx[0] * DIM + t];
        float c1 = kb[(size_t)fidx[1] * DIM + t];
        float c2 = kb[(size_t)fidx[2] * DIM + t];
        ctx_out[(size_t)q * DIM + t] = ((c0 + c1) + c2) / 3.0f;
    }
}

// ---------- kernel 3: MLP tail (attn == 1 identically; q/k are dead code) ----------
__global__ void mlp_kernel(const float* __restrict__ emb,
                           const float* __restrict__ ctx,
                           const float* __restrict__ in_proj_w,
                           const float* __restrict__ in_proj_b,
                           const float* __restrict__ out_w,
                           const float* __restrict__ out_b,
                           const float* __restrict__ ci_w1,
                           const float* __restrict__ ci_b1,
                           const float* __restrict__ ci_w2,
                           const float* __restrict__ ci_b2,
                           const float* __restrict__ cls_w1,
                           const float* __restrict__ cls_b1,
                           const float* __restrict__ cls_w2,
                           const float* __restrict__ cls_b2,
                           float* __restrict__ pred) {
    __shared__ float se[64], sc[64], sv[64], sa[64], sh[64], senh[64], scc[128];
    const int b = blockIdx.x, t = threadIdx.x;

    if (t < 64) { se[t] = emb[b * 64 + t]; sc[t] = ctx[b * 64 + t]; }
    __syncthreads();
    if (t < 64) {
        const float* w = in_proj_w + (size_t)(128 + t) * 64;
        float s = in_proj_b[128 + t];
        #pragma unroll 8
        for (int d = 0; d < 64; d++) s += sc[d] * w[d];
        sv[t] = s;
    }
    __syncthreads();
    if (t < 64) {
        const float* w = out_w + (size_t)t * 64;
        float s = out_b[t];
        #pragma unroll 8
        for (int d = 0; d < 64; d++) s += sv[d] * w[d];
        sa[t] = s;
    }
    __syncthreads();
    if (t < 64) {
        const float* w = ci_w1 + (size_t)t * 128;
        float s = ci_b1[t];
        #pragma unroll 8
        for (int d = 0; d < 64; d++) s += se[d] * w[d];
        #pragma unroll 8
        for (int d = 0; d < 64; d++) s += sa[d] * w[64 + d];
        sh[t] = fmaxf(s, 0.f);
    }
    __syncthreads();
    if (t < 64) {
        const float* w = ci_w2 + (size_t)t * 64;
        float s = ci_b2[t];
        #pragma unroll 8
        for (int d = 0; d < 64; d++) s += sh[d] * w[d];
        senh[t] = s;
    }
    __syncthreads();
    {
        const float* w = cls_w1 + (size_t)t * 64;
        float s = cls_b1[t];
        #pragma unroll 8
        for (int d = 0; d < 64; d++) s += senh[d] * w[d];
        scc[t] = fmaxf(s, 0.f);
    }
    __syncthreads();
    if (t < 2) {
        const float* w = cls_w2 + (size_t)t * 128;
        float s = cls_b2[t];
        for (int d = 0; d < 128; d++) s += scc[d] * w[d];
        pred[b * 2 + t] = s;
    }
}

extern "C" void kernel_launch(void* const* d_in, const int* in_sizes, int n_in,
                              void* d_out, int out_size, void* d_ws, size_t ws_size,
                              hipStream_t stream) {
    const float* emb       = (const float*)d_in[0];
    const float* kb        = (const float*)d_in[1];
    const float* in_proj_w = (const float*)d_in[2];
    const float* in_proj_b = (const float*)d_in[3];
    const float* out_w     = (const float*)d_in[4];
    const float* out_b     = (const float*)d_in[5];
    const float* ci_w1     = (const float*)d_in[6];
    const float* ci_b1     = (const float*)d_in[7];
    const float* ci_w2     = (const float*)d_in[8];
    const float* ci_b2     = (const float*)d_in[9];
    const float* cls_w1    = (const float*)d_in[10];
    const float* cls_b1    = (const float*)d_in[11];
    const float* cls_w2    = (const float*)d_in[12];
    const float* cls_b2    = (const float*)d_in[13];
    float* out = (float*)d_out;

    const int Bq = in_sizes[0] / DIM;   // 256
    const int N  = in_sizes[1] / DIM;   // 1,000,000

    float* qunit = (float*)d_ws;
    const size_t qunit_bytes = (size_t)Bq * DIM * 4;
    long avail = (long)ws_size - (long)qunit_bytes;
    int NB = (int)(avail / ((long)Bq * 3 * 8));
    if (NB > 1024) NB = 1024;
    if (NB < 1)    NB = 1;
    float* tv = qunit + (size_t)Bq * DIM;
    int*   ti = (int*)(tv + (size_t)Bq * NB * 3);
    const int rpb = (N + NB - 1) / NB;   // NB=1024 -> rpb=977 -> nch=16 (6-bit tag ok)

    float* ctx_out  = out + (size_t)Bq * 2;
    float* pred_out = out;

    qunit_kernel<<<Bq, 64, 0, stream>>>(emb, qunit);
    score_topk_kernel<<<NB * QSPLIT, 256, 0, stream>>>(kb, qunit, tv, ti, NB, N, rpb);
    merge_rescore_kernel<<<Bq, 256, 0, stream>>>(tv, ti, kb, qunit, ctx_out, NB, N);
    mlp_kernel<<<Bq, 128, 0, stream>>>(emb, ctx_out, in_proj_w, in_proj_b,
                                       out_w, out_b, ci_w1, ci_b1, ci_w2, ci_b2,
                                       cls_w1, cls_b1, cls_w2, cls_b2, pred_out);
}